// Round 11
// baseline (218.323 us; speedup 1.0000x reference)
//
#include <hip/hip_runtime.h>
#include <hip/hip_bf16.h>
#include <hip/hip_cooperative_groups.h>
#include <stdint.h>

namespace cg = cooperative_groups;

#define N_NODES 16384   // B*H*W
#define NPB     4096    // nodes per batch
#define NB      4
#define KNN     4
#define NEDGE   (N_NODES * 5)
#define WIN     12      // sorted-order window radius for exact 1-D kNN
#define NBUK    4096

typedef short bf16x8 __attribute__((ext_vector_type(8)));
typedef float f32x4 __attribute__((ext_vector_type(4)));

__device__ __forceinline__ unsigned short f2bf(float f) {
  unsigned u = __float_as_uint(f);
  unsigned r = (u + 0x7fff + ((u >> 16) & 1)) >> 16;   // RNE
  return (unsigned short)r;
}
__device__ __forceinline__ float bf2f(unsigned short u) {
  return __uint_as_float(((unsigned)u) << 16);
}

// ---- cooperative fused graph build: 64 blocks x 256 threads (wide fusion) ----
// Counting sort by density bucket + exact (value,idx) in-bucket order, windowed
// exact top-5 by (dist,idx), degree scan, CSR fill. Semantics == R7-R10 pipeline.
__global__ __launch_bounds__(256)
void graph_build_coop(const float* __restrict__ dm,
                      unsigned long long* __restrict__ tmpkeys,
                      unsigned long long* __restrict__ skeys,
                      int* __restrict__ rank,
                      int* __restrict__ bhist, int* __restrict__ bstart,
                      int* __restrict__ bcur,
                      int* __restrict__ deg, float* __restrict__ dinv,
                      int* __restrict__ off, int* __restrict__ cur,
                      int* __restrict__ srcs) {
  cg::grid_group grid = cg::this_grid();
  __shared__ int part[256];
  const int gid = blockIdx.x * 256 + threadIdx.x;   // [0,16384)
  const int b = gid >> 12, li = gid & (NPB - 1);

  // S1: init deg/hist; load density, form key+bucket
  deg[gid] = 1;
  bhist[gid] = 0;
  float v = dm[gid];
  const unsigned long long key =
      (((unsigned long long)__float_as_uint(v)) << 32) | (unsigned)li;
  int bk = (int)(v * (float)NBUK); if (bk > NBUK - 1) bk = NBUK - 1;
  __threadfence(); grid.sync();

  // S2: histogram
  atomicAdd(&bhist[b * NBUK + bk], 1);
  __threadfence(); grid.sync();

  // S3: exclusive scan of bucket counts (block 0)
  if (blockIdx.x == 0) {
    int t = threadIdx.x, base = t * 64, s = 0;
    for (int i = 0; i < 64; ++i) s += bhist[base + i];
    part[t] = s;
    __syncthreads();
    if (t == 0) { int a = 0; for (int i = 0; i < 256; ++i) { int x = part[i]; part[i] = a; a += x; } }
    __syncthreads();
    int a = part[t];
    for (int i = 0; i < 64; ++i) { bstart[base + i] = a; bcur[base + i] = a; a += bhist[base + i]; }
    if (t == 255) bstart[N_NODES] = N_NODES;
  }
  __threadfence(); grid.sync();

  // S4: scatter key into bucket slot
  { int slot = atomicAdd(&bcur[b * NBUK + bk], 1); tmpkeys[slot] = key; }
  __threadfence(); grid.sync();

  // S5: finalize exact in-bucket order (gid = global bucket id); batch-local rank
  {
    int s0 = bstart[gid], s1 = bstart[gid + 1];
    int batch_base = (gid >> 12) << 12;
    for (int i = s0; i < s1; ++i) {
      unsigned long long ki = tmpkeys[i];
      int r = 0;
      for (int j = s0; j < s1; ++j) r += (tmpkeys[j] < ki);
      skeys[s0 + r] = ki;
      rank[batch_base + (int)(ki & 0xffffffffull)] = (s0 + r) - batch_base;
    }
  }
  __threadfence(); grid.sync();

  // S6: windowed exact top-5 by (dist,idx); targets stay in registers
  int t0, t1, t2, t3;
  {
    int p = rank[gid];
    const unsigned long long* sk = skeys + b * NPB;
    int lo = p - WIN; if (lo < 0) lo = 0;
    int hi = p + WIN; if (hi > NPB - 1) hi = NPB - 1;
    unsigned long long k0 = ~0ull, k1 = ~0ull, k2 = ~0ull, k3 = ~0ull, k4 = ~0ull;
    for (int q = lo; q <= hi; ++q) {
      unsigned long long kq = sk[q];
      float vq = __uint_as_float((unsigned)(kq >> 32));
      float dist = fabsf(v - vq);
      unsigned long long dk = (((unsigned long long)__float_as_uint(dist)) << 32) |
                              (kq & 0xffffffffull);
      if (dk < k4) {
        if (dk < k0)      { k4 = k3; k3 = k2; k2 = k1; k1 = k0; k0 = dk; }
        else if (dk < k1) { k4 = k3; k3 = k2; k2 = k1; k1 = dk; }
        else if (dk < k2) { k4 = k3; k3 = k2; k2 = dk; }
        else if (dk < k3) { k4 = k3; k3 = dk; }
        else              { k4 = dk; }
      }
    }
    int base = b * NPB;
    t0 = base + (int)(k1 & 0xffffffffull);
    t1 = base + (int)(k2 & 0xffffffffull);
    t2 = base + (int)(k3 & 0xffffffffull);
    t3 = base + (int)(k4 & 0xffffffffull);
    atomicAdd(&deg[t0], 1); atomicAdd(&deg[t1], 1);
    atomicAdd(&deg[t2], 1); atomicAdd(&deg[t3], 1);
  }
  __threadfence(); grid.sync();

  // S7: degree scan -> off/cur/dinv (block 0)
  if (blockIdx.x == 0) {
    int t = threadIdx.x, base = t * 64, s = 0;
    for (int i = 0; i < 64; ++i) s += deg[base + i];
    part[t] = s;
    __syncthreads();
    if (t == 0) { int a = 0; for (int i = 0; i < 256; ++i) { int x = part[i]; part[i] = a; a += x; } }
    __syncthreads();
    int a = part[t];
    for (int i = 0; i < 64; ++i) {
      int dg = deg[base + i];
      off[base + i] = a; cur[base + i] = a;
      dinv[base + i] = rsqrtf((float)dg);
      a += dg;
    }
    if (t == 255) off[N_NODES] = NEDGE;
  }
  __threadfence(); grid.sync();

  // S8: CSR fill (4 kNN targets + self), sources are global node ids
  {
    int pos;
    pos = atomicAdd(&cur[t0], 1);  srcs[pos] = gid;
    pos = atomicAdd(&cur[t1], 1);  srcs[pos] = gid;
    pos = atomicAdd(&cur[t2], 1);  srcs[pos] = gid;
    pos = atomicAdd(&cur[t3], 1);  srcs[pos] = gid;
    pos = atomicAdd(&cur[gid], 1); srcs[pos] = gid;
  }
}

// ---- both weight transposes ([K][N]f32 -> [N][K]bf16) in ONE kernel ----
__global__ void weights_cvt_kernel(const float* __restrict__ W1, unsigned short* __restrict__ W1t,
                                   const float* __restrict__ W2, unsigned short* __restrict__ W2t) {
  __shared__ float tile[32][33];
  int id = blockIdx.x;
  const float* in; unsigned short* out; int Rin, Cin, c0, r0;
  if (id < 128) { in = W1; out = W1t; Rin = 256; Cin = 512; c0 = (id & 15) * 32; r0 = (id >> 4) * 32; }
  else { id -= 128; in = W2; out = W2t; Rin = 512; Cin = 256; c0 = (id & 7) * 32; r0 = (id >> 3) * 32; }
  int tx = threadIdx.x & 31, ty = threadIdx.x >> 5;
  const float* ip = in + (size_t)r0 * Cin + c0;
#pragma unroll
  for (int i = 0; i < 32; i += 8) tile[ty + i][tx] = ip[(size_t)(ty + i) * Cin + tx];
  __syncthreads();
  unsigned short* op = out + (size_t)c0 * Rin + r0;
#pragma unroll
  for (int i = 0; i < 32; i += 8) op[(size_t)(ty + i) * Rin + tx] = f2bf(tile[tx][ty + i]);
}

// ---- batched transpose + cvt bf16: [B][Rin][Cin]f32 -> [B][Cin][Rin]bf16 ----
__global__ void transpose_cvt_bf16_kernel(const float* __restrict__ in,
                                          unsigned short* __restrict__ out,
                                          int Rin, int Cin) {
  __shared__ float tile[32][33];
  int c0 = blockIdx.x * 32, r0 = blockIdx.y * 32, b = blockIdx.z;
  int tx = threadIdx.x & 31, ty = threadIdx.x >> 5;
  const float* ip = in + ((size_t)b * Rin + r0) * Cin + c0;
#pragma unroll
  for (int i = 0; i < 32; i += 8) tile[ty + i][tx] = ip[(size_t)(ty + i) * Cin + tx];
  __syncthreads();
  unsigned short* op = out + ((size_t)b * Cin + c0) * Rin + r0;
#pragma unroll
  for (int i = 0; i < 32; i += 8) op[(size_t)(ty + i) * Rin + tx] = f2bf(tile[tx][ty + i]);
}

// ---- fp32 batched transpose: [B][Rin][Cin] -> [B][Cin][Rin] ----
__global__ void transpose_kernel(const float* __restrict__ in, float* __restrict__ out,
                                 int Rin, int Cin) {
  __shared__ float tile[32][33];
  int c0 = blockIdx.x * 32, r0 = blockIdx.y * 32, b = blockIdx.z;
  int tx = threadIdx.x & 31, ty = threadIdx.x >> 5;
  const float* ip = in + ((size_t)b * Rin + r0) * Cin + c0;
#pragma unroll
  for (int i = 0; i < 32; i += 8) tile[ty + i][tx] = ip[(size_t)(ty + i) * Cin + tx];
  __syncthreads();
  float* op = out + ((size_t)b * Cin + c0) * Rin + r0;
#pragma unroll
  for (int i = 0; i < 32; i += 8) op[(size_t)(ty + i) * Rin + tx] = tile[tx][ty + i];
}

// ---- propagate (bf16 in -> bf16 out), 4 nodes/block, C=256 ----
__global__ void prop_kernel(const unsigned short* __restrict__ in,
                            unsigned short* __restrict__ out,
                            const int* __restrict__ off, const int* __restrict__ srcs,
                            const float* __restrict__ dinv) {
  int i = blockIdx.x * 4 + (threadIdx.x >> 6);
  int l = threadIdx.x & 63;
  int e0 = off[i], e1 = off[i + 1];
  float ax = 0.f, ay = 0.f, az = 0.f, aw = 0.f;
  for (int e = e0; e < e1; ++e) {
    int j = srcs[e];
    float dj = dinv[j];
    ushort4 u = *(const ushort4*)(in + (size_t)j * 256 + l * 4);
    ax = fmaf(dj, bf2f(u.x), ax); ay = fmaf(dj, bf2f(u.y), ay);
    az = fmaf(dj, bf2f(u.z), az); aw = fmaf(dj, bf2f(u.w), aw);
  }
  float di = dinv[i];
  ushort4 o;
  o.x = f2bf(ax * di); o.y = f2bf(ay * di);
  o.z = f2bf(az * di); o.w = f2bf(aw * di);
  *(ushort4*)(out + (size_t)i * 256 + l * 4) = o;
}

// ---- propagate + bias + relu (bf16 in -> f32 out node-major), 4 nodes/block ----
__global__ void prop2_kernel(const unsigned short* __restrict__ in,
                             float* __restrict__ out,
                             const int* __restrict__ off, const int* __restrict__ srcs,
                             const float* __restrict__ dinv, const float* __restrict__ bias) {
  int i = blockIdx.x * 4 + (threadIdx.x >> 6);
  int l = threadIdx.x & 63;
  int e0 = off[i], e1 = off[i + 1];
  float ax = 0.f, ay = 0.f, az = 0.f, aw = 0.f;
  for (int e = e0; e < e1; ++e) {
    int j = srcs[e];
    float dj = dinv[j];
    ushort4 u = *(const ushort4*)(in + (size_t)j * 256 + l * 4);
    ax = fmaf(dj, bf2f(u.x), ax); ay = fmaf(dj, bf2f(u.y), ay);
    az = fmaf(dj, bf2f(u.z), az); aw = fmaf(dj, bf2f(u.w), aw);
  }
  float di = dinv[i];
  float4 o;
  o.x = fmaxf(ax * di + bias[l * 4 + 0], 0.f);
  o.y = fmaxf(ay * di + bias[l * 4 + 1], 0.f);
  o.z = fmaxf(az * di + bias[l * 4 + 2], 0.f);
  o.w = fmaxf(aw * di + bias[l * 4 + 3], 0.f);
  *(float4*)(out + (size_t)i * 256 + l * 4) = o;
}

// ---- bf16 MFMA GEMM: C[M,N] = A[M,K] @ Bt[N,K]^T (+bias, relu) ----
// 64x128 tile (was 128x128): 2x the blocks -> 4-6 blocks/CU for latency hiding
// of the shallow-K barrier-drain loop. 4 waves, each 64 rows x 32 cols.
template <bool BIAS_RELU, bool OUT_BF16>
__global__ __launch_bounds__(256)
void gemm_bf16_kernel(const unsigned short* __restrict__ A,
                      const unsigned short* __restrict__ Bt,
                      void* __restrict__ C, const float* __restrict__ bias,
                      int M, int N, int K) {
  __shared__ char lds[24576];   // A: [64][128B] @0 ; B: [128][128B] @8192
  const int tid = threadIdx.x;
  const int l = tid & 63, w = tid >> 6;
  const int bm = blockIdx.x * 64, bn = blockIdx.y * 128;
  f32x4 acc[4][2] = {};

  for (int k0 = 0; k0 < K; k0 += 64) {
    __syncthreads();
#pragma unroll
    for (int q = 0; q < 2; ++q) {          // A tile: 8KB
      int o = q * 4096 + tid * 16;
      int r = o >> 7;                      // 0..63
      int gc = ((o >> 4) & 7) ^ (r & 7);
      const char* srcA = (const char*)A + ((size_t)(bm + r) * K + k0) * 2 + gc * 16;
      __builtin_amdgcn_global_load_lds(
          (const __attribute__((address_space(1))) void*)srcA,
          (__attribute__((address_space(3))) void*)(lds + o), 16, 0, 0);
    }
#pragma unroll
    for (int q = 0; q < 4; ++q) {          // B tile: 16KB
      int o = q * 4096 + tid * 16;
      int r = o >> 7;                      // 0..127
      int gc = ((o >> 4) & 7) ^ (r & 7);
      const char* srcB = (const char*)Bt + ((size_t)(bn + r) * K + k0) * 2 + gc * 16;
      __builtin_amdgcn_global_load_lds(
          (const __attribute__((address_space(1))) void*)srcB,
          (__attribute__((address_space(3))) void*)(lds + 8192 + o), 16, 0, 0);
    }
    __syncthreads();

#pragma unroll
    for (int kk = 0; kk < 64; kk += 32) {
      bf16x8 af[4], bf[2];
      int gc = (kk >> 3) + (l >> 4);
#pragma unroll
      for (int mi = 0; mi < 4; ++mi) {
        int r = mi * 16 + (l & 15);
        af[mi] = *(const bf16x8*)(lds + r * 128 + ((gc ^ (r & 7)) << 4));
      }
#pragma unroll
      for (int ni = 0; ni < 2; ++ni) {
        int r = w * 32 + ni * 16 + (l & 15);
        bf[ni] = *(const bf16x8*)(lds + 8192 + r * 128 + ((gc ^ (r & 7)) << 4));
      }
#pragma unroll
      for (int mi = 0; mi < 4; ++mi)
#pragma unroll
        for (int ni = 0; ni < 2; ++ni)
          acc[mi][ni] = __builtin_amdgcn_mfma_f32_16x16x32_bf16(af[mi], bf[ni],
                                                                acc[mi][ni], 0, 0, 0);
    }
  }

#pragma unroll
  for (int mi = 0; mi < 4; ++mi) {
#pragma unroll
    for (int ni = 0; ni < 2; ++ni) {
      int row0 = bm + mi * 16 + ((l >> 4) << 2);
      int col = bn + w * 32 + ni * 16 + (l & 15);
      float bv = BIAS_RELU ? bias[col] : 0.f;
      f32x4 v = acc[mi][ni];
#pragma unroll
      for (int r = 0; r < 4; ++r) {
        float val = v[r];
        if (BIAS_RELU) val = fmaxf(val + bv, 0.f);
        if (OUT_BF16)
          ((unsigned short*)C)[(size_t)(row0 + r) * N + col] = f2bf(val);
        else
          ((float*)C)[(size_t)(row0 + r) * N + col] = val;
      }
    }
  }
}

// ---- launch ----
extern "C" void kernel_launch(void* const* d_in, const int* in_sizes, int n_in,
                              void* d_out, int out_size, void* d_ws, size_t ws_size,
                              hipStream_t stream) {
  const float* dm = (const float*)d_in[0];
  const float* fm = (const float*)d_in[1];
  const float* W1 = (const float*)d_in[2];
  const float* b1 = (const float*)d_in[3];
  const float* W2 = (const float*)d_in[4];
  const float* b2 = (const float*)d_in[5];
  float* out = (float*)d_out;

  char* ws = (char*)d_ws;
  int*                deg   = (int*)(ws + 0x040000);
  float*              dinv  = (float*)(ws + 0x050000);
  int*                off   = (int*)(ws + 0x060000);
  int*                cur   = (int*)(ws + 0x080000);
  int*                srcs  = (int*)(ws + 0x0A0000);
  unsigned long long* skeys = (unsigned long long*)(ws + 0x100000);
  int*                rank  = (int*)(ws + 0x120000);
  int*                bhist = (int*)(ws + 0x130000);
  int*                bstart= (int*)(ws + 0x140000);
  int*                bcur  = (int*)(ws + 0x160000);
  unsigned long long* tmpkeys = (unsigned long long*)(ws + 0x170000);
  unsigned short*     W1t   = (unsigned short*)(ws + 0x190000);
  unsigned short*     W2t   = (unsigned short*)(ws + 0x1D0000);
  unsigned short*     px0   = (unsigned short*)(ws + 0x0400000);
  unsigned short*     px    = (unsigned short*)(ws + 0x0C00000);
  unsigned short*     h1    = (unsigned short*)(ws + 0x1400000);
  unsigned short*     t2    = (unsigned short*)(ws + 0x2400000);
  float*              xout  = (float*)(ws + 0x2C00000);
  (void)ws_size; (void)in_sizes; (void)n_in; (void)out_size;

  // graph build: single cooperative kernel, 64 blocks (wide fusion)
  {
    const float* a0 = dm;
    unsigned long long* a1 = tmpkeys; unsigned long long* a2 = skeys;
    int* a3 = rank; int* a4 = bhist; int* a5 = bstart; int* a6 = bcur;
    int* a7 = deg; float* a8 = dinv; int* a9 = off; int* a10 = cur; int* a11 = srcs;
    void* args[] = {&a0, &a1, &a2, &a3, &a4, &a5, &a6, &a7, &a8, &a9, &a10, &a11};
    hipLaunchCooperativeKernel((const void*)graph_build_coop, dim3(64), dim3(256),
                               args, 0, stream);
  }

  // weights -> bf16 [N][K]
  weights_cvt_kernel<<<256, 256, 0, stream>>>(W1, W1t, W2, W2t);

  // feature maps -> node-major bf16
  transpose_cvt_bf16_kernel<<<dim3(128, 8, NB), 256, 0, stream>>>(fm, px0, 256, 4096);

  // layer 1: propagate then GEMM relu(.@W1+b1) -> bf16
  prop_kernel<<<N_NODES / 4, 256, 0, stream>>>(px0, px, off, srcs, dinv);
  gemm_bf16_kernel<true, true><<<dim3(256, 4), 256, 0, stream>>>(
      px, W1t, h1, b1, 16384, 512, 256);

  // layer 2: GEMM h1@W2 -> bf16, then propagate+bias+relu (f32 node-major)
  gemm_bf16_kernel<false, true><<<dim3(256, 2), 256, 0, stream>>>(
      h1, W2t, t2, nullptr, 16384, 256, 512);
  prop2_kernel<<<N_NODES / 4, 256, 0, stream>>>(t2, xout, off, srcs, dinv, b2);

  // node-major -> [B][256][4096]
  transpose_kernel<<<dim3(8, 128, NB), 256, 0, stream>>>(xout, out, 4096, 256);
}

// Round 12
// 126.154 us; speedup vs baseline: 1.7306x; 1.7306x over previous
//
#include <hip/hip_runtime.h>
#include <hip/hip_bf16.h>
#include <stdint.h>

#define N_NODES 16384   // B*H*W
#define NPB     4096    // nodes per batch
#define NB      4
#define KNN     4
#define NEDGE   (N_NODES * 5)
#define WIN     12      // sorted-order window radius for exact 1-D kNN
#define NBUK    4096

typedef short bf16x8 __attribute__((ext_vector_type(8)));
typedef float f32x4 __attribute__((ext_vector_type(4)));

__device__ __forceinline__ unsigned short f2bf(float f) {
  unsigned u = __float_as_uint(f);
  unsigned r = (u + 0x7fff + ((u >> 16) & 1)) >> 16;   // RNE
  return (unsigned short)r;
}
__device__ __forceinline__ float bf2f(unsigned short u) {
  return __uint_as_float(((unsigned)u) << 16);
}

// ---------------- S1: init (deg=1, bucket hist=0) ----------------
__global__ void init_kernel(int* __restrict__ deg, int* __restrict__ bhist) {
  int i = blockIdx.x * 256 + threadIdx.x;
  if (i < N_NODES) { deg[i] = 1; bhist[i] = 0; }
}

// ---------------- S2: bucket histogram ----------------
__global__ void hist_kernel(const float* __restrict__ dm, int* __restrict__ bhist) {
  int e = blockIdx.x * 256 + threadIdx.x;
  if (e >= N_NODES) return;
  int b = e >> 12;
  float v = dm[e];
  int bk = (int)(v * (float)NBUK); if (bk > NBUK - 1) bk = NBUK - 1;
  atomicAdd(&bhist[b * NBUK + bk], 1);
}

// ---------------- S3: exclusive scan of 16384 bucket counts ----------------
__global__ void bscan_kernel(const int* __restrict__ bhist, int* __restrict__ bstart,
                             int* __restrict__ bcur) {
  __shared__ int part[256];
  int t = threadIdx.x;
  int base = t * 64;
  int s = 0;
  for (int i = 0; i < 64; ++i) s += bhist[base + i];
  part[t] = s;
  __syncthreads();
  if (t == 0) {
    int acc = 0;
    for (int i = 0; i < 256; ++i) { int v = part[i]; part[i] = acc; acc += v; }
  }
  __syncthreads();
  int acc = part[t];
  for (int i = 0; i < 64; ++i) {
    bstart[base + i] = acc;
    bcur[base + i] = acc;
    acc += bhist[base + i];
  }
  if (t == 255) bstart[N_NODES] = N_NODES;
}

// ---------------- S4: scatter keys into bucket slots ----------------
__global__ void scatter_kernel(const float* __restrict__ dm, int* __restrict__ bcur,
                               unsigned long long* __restrict__ tmpkeys) {
  int e = blockIdx.x * 256 + threadIdx.x;
  if (e >= N_NODES) return;
  int b = e >> 12, li = e & (NPB - 1);
  float v = dm[e];
  int bk = (int)(v * (float)NBUK); if (bk > NBUK - 1) bk = NBUK - 1;
  int slot = atomicAdd(&bcur[b * NBUK + bk], 1);
  tmpkeys[slot] = (((unsigned long long)__float_as_uint(v)) << 32) | (unsigned)li;
}

// ---------------- S5: finalize — exact (value,idx) order within bucket ----------
__global__ void bfinal_kernel(const unsigned long long* __restrict__ tmpkeys,
                              const int* __restrict__ bstart,
                              unsigned long long* __restrict__ skeys,
                              int* __restrict__ rank) {
  int g = blockIdx.x * 256 + threadIdx.x;   // global bucket id
  if (g >= N_NODES) return;
  int s0 = bstart[g], s1 = bstart[g + 1];
  int cnt = s1 - s0;
  if (cnt <= 0) return;
  int batch_base = (g >> 12) << 12;
  if (cnt == 1) {
    unsigned long long k = tmpkeys[s0];
    skeys[s0] = k;
    rank[batch_base + (int)(k & 0xffffffffull)] = s0 - batch_base;
    return;
  }
  for (int i = s0; i < s1; ++i) {
    unsigned long long ki = tmpkeys[i];
    int r = 0;
    for (int j = s0; j < s1; ++j) r += (tmpkeys[j] < ki);
    skeys[s0 + r] = ki;
    rank[batch_base + (int)(ki & 0xffffffffull)] = (s0 + r) - batch_base;
  }
}

// ---------------- kNN select: exact top-5 by (dist,idx) within sorted window -----
__global__ void knn_select_kernel(const unsigned long long* __restrict__ skeys,
                                  const int* __restrict__ rank,
                                  int* __restrict__ tgt, int* __restrict__ deg) {
  int node = blockIdx.x * 256 + threadIdx.x;
  if (node >= N_NODES) return;
  int b = node >> 12;
  int p = rank[node];
  const unsigned long long* sk = skeys + b * NPB;
  float di = __uint_as_float((unsigned)(sk[p] >> 32));
  int lo = p - WIN; if (lo < 0) lo = 0;
  int hi = p + WIN; if (hi > NPB - 1) hi = NPB - 1;
  unsigned long long k0 = ~0ull, k1 = ~0ull, k2 = ~0ull, k3 = ~0ull, k4 = ~0ull;
  for (int q = lo; q <= hi; ++q) {
    unsigned long long key = sk[q];
    float v = __uint_as_float((unsigned)(key >> 32));
    float dist = fabsf(di - v);
    unsigned long long dk = (((unsigned long long)__float_as_uint(dist)) << 32) |
                            (key & 0xffffffffull);
    if (dk < k4) {
      if (dk < k0)      { k4 = k3; k3 = k2; k2 = k1; k1 = k0; k0 = dk; }
      else if (dk < k1) { k4 = k3; k3 = k2; k2 = k1; k1 = dk; }
      else if (dk < k2) { k4 = k3; k3 = k2; k2 = dk; }
      else if (dk < k3) { k4 = k3; k3 = dk; }
      else              { k4 = dk; }
    }
  }
  int base = b * NPB;
  int t0 = base + (int)(k1 & 0xffffffffull);
  int t1 = base + (int)(k2 & 0xffffffffull);
  int t2 = base + (int)(k3 & 0xffffffffull);
  int t3 = base + (int)(k4 & 0xffffffffull);
  tgt[node * KNN + 0] = t0; atomicAdd(&deg[t0], 1);
  tgt[node * KNN + 1] = t1; atomicAdd(&deg[t1], 1);
  tgt[node * KNN + 2] = t2; atomicAdd(&deg[t2], 1);
  tgt[node * KNN + 3] = t3; atomicAdd(&deg[t3], 1);
}

// ---------------- dinv + exclusive scan of deg (single block) ----------------
__global__ void scan_kernel(const int* __restrict__ deg, float* __restrict__ dinv,
                            int* __restrict__ off, int* __restrict__ cur) {
  __shared__ int part[256];
  int t = threadIdx.x;
  int base = t * 64;
  int s = 0;
  for (int i = 0; i < 64; ++i) s += deg[base + i];
  part[t] = s;
  __syncthreads();
  if (t == 0) {
    int acc = 0;
    for (int i = 0; i < 256; ++i) { int v = part[i]; part[i] = acc; acc += v; }
  }
  __syncthreads();
  int acc = part[t];
  for (int i = 0; i < 64; ++i) {
    int dg = deg[base + i];
    off[base + i] = acc;
    cur[base + i] = acc;
    dinv[base + i] = rsqrtf((float)dg);
    acc += dg;
  }
  if (t == 255) off[N_NODES] = acc;  // == NEDGE
}

// ---------------- CSR fill ----------------
__global__ void fill_csr_kernel(const int* __restrict__ tgt, int* __restrict__ cur,
                                int* __restrict__ srcs) {
  int e = blockIdx.x * 256 + threadIdx.x;
  if (e >= NEDGE) return;
  int j = e / 5, q = e - j * 5;
  int target = (q < KNN) ? tgt[j * KNN + q] : j;
  int pos = atomicAdd(&cur[target], 1);
  srcs[pos] = j;
}

// ---- both weight transposes ([K][N]f32 -> [N][K]bf16) in ONE kernel ----
__global__ void weights_cvt_kernel(const float* __restrict__ W1, unsigned short* __restrict__ W1t,
                                   const float* __restrict__ W2, unsigned short* __restrict__ W2t) {
  __shared__ float tile[32][33];
  int id = blockIdx.x;
  const float* in; unsigned short* out; int Rin, Cin, c0, r0;
  if (id < 128) { in = W1; out = W1t; Rin = 256; Cin = 512; c0 = (id & 15) * 32; r0 = (id >> 4) * 32; }
  else { id -= 128; in = W2; out = W2t; Rin = 512; Cin = 256; c0 = (id & 7) * 32; r0 = (id >> 3) * 32; }
  int tx = threadIdx.x & 31, ty = threadIdx.x >> 5;
  const float* ip = in + (size_t)r0 * Cin + c0;
#pragma unroll
  for (int i = 0; i < 32; i += 8) tile[ty + i][tx] = ip[(size_t)(ty + i) * Cin + tx];
  __syncthreads();
  unsigned short* op = out + (size_t)c0 * Rin + r0;
#pragma unroll
  for (int i = 0; i < 32; i += 8) op[(size_t)(ty + i) * Rin + tx] = f2bf(tile[tx][ty + i]);
}

// ---- batched transpose + cvt bf16: [B][Rin][Cin]f32 -> [B][Cin][Rin]bf16 ----
__global__ void transpose_cvt_bf16_kernel(const float* __restrict__ in,
                                          unsigned short* __restrict__ out,
                                          int Rin, int Cin) {
  __shared__ float tile[32][33];
  int c0 = blockIdx.x * 32, r0 = blockIdx.y * 32, b = blockIdx.z;
  int tx = threadIdx.x & 31, ty = threadIdx.x >> 5;
  const float* ip = in + ((size_t)b * Rin + r0) * Cin + c0;
#pragma unroll
  for (int i = 0; i < 32; i += 8) tile[ty + i][tx] = ip[(size_t)(ty + i) * Cin + tx];
  __syncthreads();
  unsigned short* op = out + ((size_t)b * Cin + c0) * Rin + r0;
#pragma unroll
  for (int i = 0; i < 32; i += 8) op[(size_t)(ty + i) * Rin + tx] = f2bf(tile[tx][ty + i]);
}

// ---- fp32 batched transpose: [B][Rin][Cin] -> [B][Cin][Rin] ----
__global__ void transpose_kernel(const float* __restrict__ in, float* __restrict__ out,
                                 int Rin, int Cin) {
  __shared__ float tile[32][33];
  int c0 = blockIdx.x * 32, r0 = blockIdx.y * 32, b = blockIdx.z;
  int tx = threadIdx.x & 31, ty = threadIdx.x >> 5;
  const float* ip = in + ((size_t)b * Rin + r0) * Cin + c0;
#pragma unroll
  for (int i = 0; i < 32; i += 8) tile[ty + i][tx] = ip[(size_t)(ty + i) * Cin + tx];
  __syncthreads();
  float* op = out + ((size_t)b * Cin + c0) * Rin + r0;
#pragma unroll
  for (int i = 0; i < 32; i += 8) op[(size_t)(ty + i) * Rin + tx] = tile[tx][ty + i];
}

// ---- propagate (bf16 in -> bf16 out), 4 nodes/block, C=256 ----
__global__ void prop_kernel(const unsigned short* __restrict__ in,
                            unsigned short* __restrict__ out,
                            const int* __restrict__ off, const int* __restrict__ srcs,
                            const float* __restrict__ dinv) {
  int i = blockIdx.x * 4 + (threadIdx.x >> 6);
  int l = threadIdx.x & 63;
  int e0 = off[i], e1 = off[i + 1];
  float ax = 0.f, ay = 0.f, az = 0.f, aw = 0.f;
  for (int e = e0; e < e1; ++e) {
    int j = srcs[e];
    float dj = dinv[j];
    ushort4 u = *(const ushort4*)(in + (size_t)j * 256 + l * 4);
    ax = fmaf(dj, bf2f(u.x), ax); ay = fmaf(dj, bf2f(u.y), ay);
    az = fmaf(dj, bf2f(u.z), az); aw = fmaf(dj, bf2f(u.w), aw);
  }
  float di = dinv[i];
  ushort4 o;
  o.x = f2bf(ax * di); o.y = f2bf(ay * di);
  o.z = f2bf(az * di); o.w = f2bf(aw * di);
  *(ushort4*)(out + (size_t)i * 256 + l * 4) = o;
}

// ---- propagate + bias + relu (bf16 in -> f32 out node-major), 4 nodes/block ----
__global__ void prop2_kernel(const unsigned short* __restrict__ in,
                             float* __restrict__ out,
                             const int* __restrict__ off, const int* __restrict__ srcs,
                             const float* __restrict__ dinv, const float* __restrict__ bias) {
  int i = blockIdx.x * 4 + (threadIdx.x >> 6);
  int l = threadIdx.x & 63;
  int e0 = off[i], e1 = off[i + 1];
  float ax = 0.f, ay = 0.f, az = 0.f, aw = 0.f;
  for (int e = e0; e < e1; ++e) {
    int j = srcs[e];
    float dj = dinv[j];
    ushort4 u = *(const ushort4*)(in + (size_t)j * 256 + l * 4);
    ax = fmaf(dj, bf2f(u.x), ax); ay = fmaf(dj, bf2f(u.y), ay);
    az = fmaf(dj, bf2f(u.z), az); aw = fmaf(dj, bf2f(u.w), aw);
  }
  float di = dinv[i];
  float4 o;
  o.x = fmaxf(ax * di + bias[l * 4 + 0], 0.f);
  o.y = fmaxf(ay * di + bias[l * 4 + 1], 0.f);
  o.z = fmaxf(az * di + bias[l * 4 + 2], 0.f);
  o.w = fmaxf(aw * di + bias[l * 4 + 3], 0.f);
  *(float4*)(out + (size_t)i * 256 + l * 4) = o;
}

// ---- bf16 MFMA GEMM: C[M,N] = A[M,K] @ Bt[N,K]^T (+bias, relu) ----
// 64x128 tile: 2x blocks vs 128x128 -> 4-6 blocks/CU hides the shallow-K
// barrier-drain (measured ~15 us win in R11). 4 waves, each 64 rows x 32 cols.
template <bool BIAS_RELU, bool OUT_BF16>
__global__ __launch_bounds__(256)
void gemm_bf16_kernel(const unsigned short* __restrict__ A,
                      const unsigned short* __restrict__ Bt,
                      void* __restrict__ C, const float* __restrict__ bias,
                      int M, int N, int K) {
  __shared__ char lds[24576];   // A: [64][128B] @0 ; B: [128][128B] @8192
  const int tid = threadIdx.x;
  const int l = tid & 63, w = tid >> 6;
  const int bm = blockIdx.x * 64, bn = blockIdx.y * 128;
  f32x4 acc[4][2] = {};

  for (int k0 = 0; k0 < K; k0 += 64) {
    __syncthreads();
#pragma unroll
    for (int q = 0; q < 2; ++q) {          // A tile: 8KB
      int o = q * 4096 + tid * 16;
      int r = o >> 7;                      // 0..63
      int gc = ((o >> 4) & 7) ^ (r & 7);
      const char* srcA = (const char*)A + ((size_t)(bm + r) * K + k0) * 2 + gc * 16;
      __builtin_amdgcn_global_load_lds(
          (const __attribute__((address_space(1))) void*)srcA,
          (__attribute__((address_space(3))) void*)(lds + o), 16, 0, 0);
    }
#pragma unroll
    for (int q = 0; q < 4; ++q) {          // B tile: 16KB
      int o = q * 4096 + tid * 16;
      int r = o >> 7;                      // 0..127
      int gc = ((o >> 4) & 7) ^ (r & 7);
      const char* srcB = (const char*)Bt + ((size_t)(bn + r) * K + k0) * 2 + gc * 16;
      __builtin_amdgcn_global_load_lds(
          (const __attribute__((address_space(1))) void*)srcB,
          (__attribute__((address_space(3))) void*)(lds + 8192 + o), 16, 0, 0);
    }
    __syncthreads();

#pragma unroll
    for (int kk = 0; kk < 64; kk += 32) {
      bf16x8 af[4], bf[2];
      int gc = (kk >> 3) + (l >> 4);
#pragma unroll
      for (int mi = 0; mi < 4; ++mi) {
        int r = mi * 16 + (l & 15);
        af[mi] = *(const bf16x8*)(lds + r * 128 + ((gc ^ (r & 7)) << 4));
      }
#pragma unroll
      for (int ni = 0; ni < 2; ++ni) {
        int r = w * 32 + ni * 16 + (l & 15);
        bf[ni] = *(const bf16x8*)(lds + 8192 + r * 128 + ((gc ^ (r & 7)) << 4));
      }
#pragma unroll
      for (int mi = 0; mi < 4; ++mi)
#pragma unroll
        for (int ni = 0; ni < 2; ++ni)
          acc[mi][ni] = __builtin_amdgcn_mfma_f32_16x16x32_bf16(af[mi], bf[ni],
                                                                acc[mi][ni], 0, 0, 0);
    }
  }

#pragma unroll
  for (int mi = 0; mi < 4; ++mi) {
#pragma unroll
    for (int ni = 0; ni < 2; ++ni) {
      int row0 = bm + mi * 16 + ((l >> 4) << 2);
      int col = bn + w * 32 + ni * 16 + (l & 15);
      float bv = BIAS_RELU ? bias[col] : 0.f;
      f32x4 v = acc[mi][ni];
#pragma unroll
      for (int r = 0; r < 4; ++r) {
        float val = v[r];
        if (BIAS_RELU) val = fmaxf(val + bv, 0.f);
        if (OUT_BF16)
          ((unsigned short*)C)[(size_t)(row0 + r) * N + col] = f2bf(val);
        else
          ((float*)C)[(size_t)(row0 + r) * N + col] = val;
      }
    }
  }
}

// ---- launch ----
extern "C" void kernel_launch(void* const* d_in, const int* in_sizes, int n_in,
                              void* d_out, int out_size, void* d_ws, size_t ws_size,
                              hipStream_t stream) {
  const float* dm = (const float*)d_in[0];
  const float* fm = (const float*)d_in[1];
  const float* W1 = (const float*)d_in[2];
  const float* b1 = (const float*)d_in[3];
  const float* W2 = (const float*)d_in[4];
  const float* b2 = (const float*)d_in[5];
  float* out = (float*)d_out;

  char* ws = (char*)d_ws;
  int*                tgt   = (int*)(ws + 0x000000);
  int*                deg   = (int*)(ws + 0x040000);
  float*              dinv  = (float*)(ws + 0x050000);
  int*                off   = (int*)(ws + 0x060000);
  int*                cur   = (int*)(ws + 0x080000);
  int*                srcs  = (int*)(ws + 0x0A0000);
  unsigned long long* skeys = (unsigned long long*)(ws + 0x100000);
  int*                rank  = (int*)(ws + 0x120000);
  int*                bhist = (int*)(ws + 0x130000);
  int*                bstart= (int*)(ws + 0x140000);
  int*                bcur  = (int*)(ws + 0x160000);
  unsigned long long* tmpkeys = (unsigned long long*)(ws + 0x170000);
  unsigned short*     W1t   = (unsigned short*)(ws + 0x190000);
  unsigned short*     W2t   = (unsigned short*)(ws + 0x1D0000);
  unsigned short*     px0   = (unsigned short*)(ws + 0x0400000);
  unsigned short*     px    = (unsigned short*)(ws + 0x0C00000);
  unsigned short*     h1    = (unsigned short*)(ws + 0x1400000);
  unsigned short*     t2    = (unsigned short*)(ws + 0x2400000);
  float*              xout  = (float*)(ws + 0x2C00000);
  (void)ws_size; (void)in_sizes; (void)n_in; (void)out_size;

  // ---- graph build: wide multi-kernel counting sort + windowed exact kNN ----
  init_kernel<<<64, 256, 0, stream>>>(deg, bhist);
  hist_kernel<<<64, 256, 0, stream>>>(dm, bhist);
  bscan_kernel<<<1, 256, 0, stream>>>(bhist, bstart, bcur);
  scatter_kernel<<<64, 256, 0, stream>>>(dm, bcur, tmpkeys);
  bfinal_kernel<<<64, 256, 0, stream>>>(tmpkeys, bstart, skeys, rank);
  knn_select_kernel<<<64, 256, 0, stream>>>(skeys, rank, tgt, deg);
  scan_kernel<<<1, 256, 0, stream>>>(deg, dinv, off, cur);
  fill_csr_kernel<<<NEDGE / 256, 256, 0, stream>>>(tgt, cur, srcs);

  // weights -> bf16 [N][K] (both in one kernel)
  weights_cvt_kernel<<<256, 256, 0, stream>>>(W1, W1t, W2, W2t);

  // feature maps -> node-major bf16
  transpose_cvt_bf16_kernel<<<dim3(128, 8, NB), 256, 0, stream>>>(fm, px0, 256, 4096);

  // layer 1: propagate then GEMM relu(.@W1+b1) -> bf16
  prop_kernel<<<N_NODES / 4, 256, 0, stream>>>(px0, px, off, srcs, dinv);
  gemm_bf16_kernel<true, true><<<dim3(256, 4), 256, 0, stream>>>(
      px, W1t, h1, b1, 16384, 512, 256);

  // layer 2: GEMM h1@W2 -> bf16, then propagate+bias+relu (f32 node-major)
  gemm_bf16_kernel<false, true><<<dim3(256, 2), 256, 0, stream>>>(
      h1, W2t, t2, nullptr, 16384, 256, 512);
  prop2_kernel<<<N_NODES / 4, 256, 0, stream>>>(t2, xout, off, srcs, dinv, b2);

  // node-major -> [B][256][4096]
  transpose_kernel<<<dim3(8, 128, NB), 256, 0, stream>>>(xout, out, 4096, 256);
}

// Round 13
// 101.124 us; speedup vs baseline: 2.1590x; 1.2475x over previous
//
#include <hip/hip_runtime.h>
#include <hip/hip_bf16.h>
#include <stdint.h>

#define N_NODES 16384   // B*H*W
#define NPB     4096    // nodes per batch
#define NB      4
#define KNN     4
#define NEDGE   (N_NODES * 5)
#define WIN     12      // sorted-order window radius for exact 1-D kNN
#define NBUK    4096

typedef short bf16x8 __attribute__((ext_vector_type(8)));
typedef float f32x4 __attribute__((ext_vector_type(4)));
typedef unsigned short u16x8 __attribute__((ext_vector_type(8)));

__device__ __forceinline__ unsigned short f2bf(float f) {
  unsigned u = __float_as_uint(f);
  unsigned r = (u + 0x7fff + ((u >> 16) & 1)) >> 16;   // RNE
  return (unsigned short)r;
}
__device__ __forceinline__ float bf2f(unsigned short u) {
  return __uint_as_float(((unsigned)u) << 16);
}

// ---- fused bucket stage: hist + scan + scatter + deg-init, one block/batch ----
// 4 blocks x 1024 threads; all counting-sort bookkeeping in LDS (52.5KB).
__global__ __launch_bounds__(1024)
void bucket_kernel(const float* __restrict__ dm,
                   unsigned long long* __restrict__ tmpkeys,
                   int* __restrict__ bstart_g, int* __restrict__ deg) {
  __shared__ int sHist[4096];
  __shared__ int sStart[4096];
  __shared__ int sCur[4096];
  __shared__ int part1[1024];
  __shared__ int part2[64];
  const int t = threadIdx.x, b = blockIdx.x;
  const float* d = dm + b * NPB;
  unsigned long long kv[4]; int bk[4];
#pragma unroll
  for (int r = 0; r < 4; ++r) {
    int i = t + r * 1024;
    sHist[i] = 0;
    deg[b * NPB + i] = 1;
  }
  __syncthreads();
#pragma unroll
  for (int r = 0; r < 4; ++r) {
    int i = t + r * 1024;
    float v = d[i];
    kv[r] = (((unsigned long long)__float_as_uint(v)) << 32) | (unsigned)i;
    int k = (int)(v * (float)NBUK); if (k > NBUK - 1) k = NBUK - 1;
    bk[r] = k;
    atomicAdd(&sHist[k], 1);
  }
  __syncthreads();
  // exclusive scan of sHist -> sStart, sCur
  part1[t] = sHist[4 * t] + sHist[4 * t + 1] + sHist[4 * t + 2] + sHist[4 * t + 3];
  __syncthreads();
  if (t < 64) {
    int s = 0;
#pragma unroll
    for (int k = 0; k < 16; ++k) s += part1[16 * t + k];
    part2[t] = s;
  }
  __syncthreads();
  if (t == 0) {
    int a = 0;
    for (int u = 0; u < 64; ++u) { int v = part2[u]; part2[u] = a; a += v; }
  }
  __syncthreads();
  {
    int base = part2[t >> 4];
    for (int k = (t >> 4) * 16; k < t; ++k) base += part1[k];
#pragma unroll
    for (int q = 0; q < 4; ++q) {
      int i = 4 * t + q;
      sStart[i] = base; sCur[i] = base;
      base += sHist[i];
    }
  }
  __syncthreads();
  // scatter to global slots; write global bucket starts
#pragma unroll
  for (int r = 0; r < 4; ++r) {
    int slot = atomicAdd(&sCur[bk[r]], 1);
    tmpkeys[b * NPB + slot] = kv[r];
  }
#pragma unroll
  for (int r = 0; r < 4; ++r) {
    int i = t + r * 1024;
    bstart_g[b * NPB + i] = b * NPB + sStart[i];
  }
  if (b == NB - 1 && t == 0) bstart_g[N_NODES] = N_NODES;
}

// ---- finalize: exact (value,idx) order within bucket (no rank array) ----
__global__ void bfinal_kernel(const unsigned long long* __restrict__ tmpkeys,
                              const int* __restrict__ bstart,
                              unsigned long long* __restrict__ skeys) {
  int g = blockIdx.x * 256 + threadIdx.x;   // global bucket id
  if (g >= N_NODES) return;
  int s0 = bstart[g], s1 = bstart[g + 1];
  int cnt = s1 - s0;
  if (cnt <= 0) return;
  if (cnt == 1) { skeys[s0] = tmpkeys[s0]; return; }
  for (int i = s0; i < s1; ++i) {
    unsigned long long ki = tmpkeys[i];
    int r = 0;
    for (int j = s0; j < s1; ++j) r += (tmpkeys[j] < ki);
    skeys[s0 + r] = ki;
  }
}

// ---- kNN select driven by sorted position (rank array eliminated) ----
__global__ void knn_select_kernel(const unsigned long long* __restrict__ skeys,
                                  int* __restrict__ tgt, int* __restrict__ deg) {
  int p = blockIdx.x * 256 + threadIdx.x;   // global sorted slot
  if (p >= N_NODES) return;
  int b = p >> 12, pl = p & (NPB - 1);
  const unsigned long long* sk = skeys + b * NPB;
  unsigned long long kp = sk[pl];
  float di = __uint_as_float((unsigned)(kp >> 32));
  int node = b * NPB + (int)(kp & 0xffffffffull);
  int lo = pl - WIN; if (lo < 0) lo = 0;
  int hi = pl + WIN; if (hi > NPB - 1) hi = NPB - 1;
  unsigned long long k0 = ~0ull, k1 = ~0ull, k2 = ~0ull, k3 = ~0ull, k4 = ~0ull;
  for (int q = lo; q <= hi; ++q) {
    unsigned long long key = sk[q];
    float v = __uint_as_float((unsigned)(key >> 32));
    float dist = fabsf(di - v);
    unsigned long long dk = (((unsigned long long)__float_as_uint(dist)) << 32) |
                            (key & 0xffffffffull);
    if (dk < k4) {
      if (dk < k0)      { k4 = k3; k3 = k2; k2 = k1; k1 = k0; k0 = dk; }
      else if (dk < k1) { k4 = k3; k3 = k2; k2 = k1; k1 = dk; }
      else if (dk < k2) { k4 = k3; k3 = k2; k2 = dk; }
      else if (dk < k3) { k4 = k3; k3 = dk; }
      else              { k4 = dk; }
    }
  }
  int base = b * NPB;
  int t0 = base + (int)(k1 & 0xffffffffull);
  int t1 = base + (int)(k2 & 0xffffffffull);
  int t2 = base + (int)(k3 & 0xffffffffull);
  int t3 = base + (int)(k4 & 0xffffffffull);
  tgt[node * KNN + 0] = t0; atomicAdd(&deg[t0], 1);
  tgt[node * KNN + 1] = t1; atomicAdd(&deg[t1], 1);
  tgt[node * KNN + 2] = t2; atomicAdd(&deg[t2], 1);
  tgt[node * KNN + 3] = t3; atomicAdd(&deg[t3], 1);
}

// ---- dinv + exclusive scan of deg (single block) ----
__global__ void scan_kernel(const int* __restrict__ deg, float* __restrict__ dinv,
                            int* __restrict__ off, int* __restrict__ cur) {
  __shared__ int part[256];
  int t = threadIdx.x;
  int base = t * 64;
  int s = 0;
  for (int i = 0; i < 64; ++i) s += deg[base + i];
  part[t] = s;
  __syncthreads();
  if (t == 0) {
    int acc = 0;
    for (int i = 0; i < 256; ++i) { int v = part[i]; part[i] = acc; acc += v; }
  }
  __syncthreads();
  int acc = part[t];
  for (int i = 0; i < 64; ++i) {
    int dg = deg[base + i];
    off[base + i] = acc;
    cur[base + i] = acc;
    dinv[base + i] = rsqrtf((float)dg);
    acc += dg;
  }
  if (t == 255) off[N_NODES] = acc;  // == NEDGE
}

// ---- CSR fill ----
__global__ void fill_csr_kernel(const int* __restrict__ tgt, int* __restrict__ cur,
                                int* __restrict__ srcs) {
  int e = blockIdx.x * 256 + threadIdx.x;
  if (e >= NEDGE) return;
  int j = e / 5, q = e - j * 5;
  int target = (q < KNN) ? tgt[j * KNN + q] : j;
  int pos = atomicAdd(&cur[target], 1);
  srcs[pos] = j;
}

// ---- combined cvt: z<4 = fm batch transpose; z==4 = both weight transposes ----
__global__ void cvt_all_kernel(const float* __restrict__ fm, unsigned short* __restrict__ px0,
                               const float* __restrict__ W1, unsigned short* __restrict__ W1t,
                               const float* __restrict__ W2, unsigned short* __restrict__ W2t) {
  __shared__ float tile[32][33];
  int z = blockIdx.z;
  const float* in; unsigned short* out; int Rin, Cin, c0, r0;
  if (z < NB) {
    in = fm + (size_t)z * 256 * 4096; out = px0 + (size_t)z * 4096 * 256;
    Rin = 256; Cin = 4096;
    c0 = blockIdx.x * 32; r0 = blockIdx.y * 32;
  } else {
    int id = blockIdx.y * 128 + blockIdx.x;
    if (id < 128)      { in = W1; out = W1t; Rin = 256; Cin = 512; c0 = (id & 15) * 32; r0 = (id >> 4) * 32; }
    else if (id < 256) { id -= 128; in = W2; out = W2t; Rin = 512; Cin = 256; c0 = (id & 7) * 32; r0 = (id >> 3) * 32; }
    else return;
  }
  int tx = threadIdx.x & 31, ty = threadIdx.x >> 5;
  const float* ip = in + (size_t)r0 * Cin + c0;
#pragma unroll
  for (int i = 0; i < 32; i += 8) tile[ty + i][tx] = ip[(size_t)(ty + i) * Cin + tx];
  __syncthreads();
  unsigned short* op = out + (size_t)c0 * Rin + r0;
#pragma unroll
  for (int i = 0; i < 32; i += 8) op[(size_t)(ty + i) * Rin + tx] = f2bf(tile[tx][ty + i]);
}

// ---- fp32 batched transpose: [B][Rin][Cin] -> [B][Cin][Rin] ----
__global__ void transpose_kernel(const float* __restrict__ in, float* __restrict__ out,
                                 int Rin, int Cin) {
  __shared__ float tile[32][33];
  int c0 = blockIdx.x * 32, r0 = blockIdx.y * 32, b = blockIdx.z;
  int tx = threadIdx.x & 31, ty = threadIdx.x >> 5;
  const float* ip = in + ((size_t)b * Rin + r0) * Cin + c0;
#pragma unroll
  for (int i = 0; i < 32; i += 8) tile[ty + i][tx] = ip[(size_t)(ty + i) * Cin + tx];
  __syncthreads();
  float* op = out + ((size_t)b * Cin + c0) * Rin + r0;
#pragma unroll
  for (int i = 0; i < 32; i += 8) op[(size_t)(ty + i) * Rin + tx] = tile[tx][ty + i];
}

// ---- propagate (bf16 -> bf16), 2 nodes/wave (half-wave rows, 16B/lane) ----
__global__ void prop_kernel(const unsigned short* __restrict__ in,
                            unsigned short* __restrict__ out,
                            const int* __restrict__ off, const int* __restrict__ srcs,
                            const float* __restrict__ dinv) {
  int i = blockIdx.x * 8 + (threadIdx.x >> 5);
  int l = threadIdx.x & 31;
  int e0 = off[i], e1 = off[i + 1];
  float a[8] = {};
  for (int e = e0; e < e1; ++e) {
    int j = srcs[e];
    float dj = dinv[j];
    u16x8 u = *(const u16x8*)(in + (size_t)j * 256 + l * 8);
#pragma unroll
    for (int k = 0; k < 8; ++k) a[k] = fmaf(dj, bf2f(u[k]), a[k]);
  }
  float di = dinv[i];
  u16x8 o;
#pragma unroll
  for (int k = 0; k < 8; ++k) o[k] = f2bf(a[k] * di);
  *(u16x8*)(out + (size_t)i * 256 + l * 8) = o;
}

// ---- propagate + bias + relu (bf16 -> f32 node-major), 2 nodes/wave ----
__global__ void prop2_kernel(const unsigned short* __restrict__ in,
                             float* __restrict__ out,
                             const int* __restrict__ off, const int* __restrict__ srcs,
                             const float* __restrict__ dinv, const float* __restrict__ bias) {
  int i = blockIdx.x * 8 + (threadIdx.x >> 5);
  int l = threadIdx.x & 31;
  int e0 = off[i], e1 = off[i + 1];
  float a[8] = {};
  for (int e = e0; e < e1; ++e) {
    int j = srcs[e];
    float dj = dinv[j];
    u16x8 u = *(const u16x8*)(in + (size_t)j * 256 + l * 8);
#pragma unroll
    for (int k = 0; k < 8; ++k) a[k] = fmaf(dj, bf2f(u[k]), a[k]);
  }
  float di = dinv[i];
  float4 o0, o1;
  o0.x = fmaxf(a[0] * di + bias[l * 8 + 0], 0.f);
  o0.y = fmaxf(a[1] * di + bias[l * 8 + 1], 0.f);
  o0.z = fmaxf(a[2] * di + bias[l * 8 + 2], 0.f);
  o0.w = fmaxf(a[3] * di + bias[l * 8 + 3], 0.f);
  o1.x = fmaxf(a[4] * di + bias[l * 8 + 4], 0.f);
  o1.y = fmaxf(a[5] * di + bias[l * 8 + 5], 0.f);
  o1.z = fmaxf(a[6] * di + bias[l * 8 + 6], 0.f);
  o1.w = fmaxf(a[7] * di + bias[l * 8 + 7], 0.f);
  *(float4*)(out + (size_t)i * 256 + l * 8) = o0;
  *(float4*)(out + (size_t)i * 256 + l * 8 + 4) = o1;
}

// ---- bf16 MFMA GEMM: C[M,N] = A[M,K] @ Bt[N,K]^T (+bias, relu), 64x128 tile ----
template <bool BIAS_RELU, bool OUT_BF16>
__global__ __launch_bounds__(256)
void gemm_bf16_kernel(const unsigned short* __restrict__ A,
                      const unsigned short* __restrict__ Bt,
                      void* __restrict__ C, const float* __restrict__ bias,
                      int M, int N, int K) {
  __shared__ char lds[24576];   // A: [64][128B] @0 ; B: [128][128B] @8192
  const int tid = threadIdx.x;
  const int l = tid & 63, w = tid >> 6;
  const int bm = blockIdx.x * 64, bn = blockIdx.y * 128;
  f32x4 acc[4][2] = {};

  for (int k0 = 0; k0 < K; k0 += 64) {
    __syncthreads();
#pragma unroll
    for (int q = 0; q < 2; ++q) {          // A tile: 8KB
      int o = q * 4096 + tid * 16;
      int r = o >> 7;
      int gc = ((o >> 4) & 7) ^ (r & 7);
      const char* srcA = (const char*)A + ((size_t)(bm + r) * K + k0) * 2 + gc * 16;
      __builtin_amdgcn_global_load_lds(
          (const __attribute__((address_space(1))) void*)srcA,
          (__attribute__((address_space(3))) void*)(lds + o), 16, 0, 0);
    }
#pragma unroll
    for (int q = 0; q < 4; ++q) {          // B tile: 16KB
      int o = q * 4096 + tid * 16;
      int r = o >> 7;
      int gc = ((o >> 4) & 7) ^ (r & 7);
      const char* srcB = (const char*)Bt + ((size_t)(bn + r) * K + k0) * 2 + gc * 16;
      __builtin_amdgcn_global_load_lds(
          (const __attribute__((address_space(1))) void*)srcB,
          (__attribute__((address_space(3))) void*)(lds + 8192 + o), 16, 0, 0);
    }
    __syncthreads();

#pragma unroll
    for (int kk = 0; kk < 64; kk += 32) {
      bf16x8 af[4], bf[2];
      int gc = (kk >> 3) + (l >> 4);
#pragma unroll
      for (int mi = 0; mi < 4; ++mi) {
        int r = mi * 16 + (l & 15);
        af[mi] = *(const bf16x8*)(lds + r * 128 + ((gc ^ (r & 7)) << 4));
      }
#pragma unroll
      for (int ni = 0; ni < 2; ++ni) {
        int r = w * 32 + ni * 16 + (l & 15);
        bf[ni] = *(const bf16x8*)(lds + 8192 + r * 128 + ((gc ^ (r & 7)) << 4));
      }
#pragma unroll
      for (int mi = 0; mi < 4; ++mi)
#pragma unroll
        for (int ni = 0; ni < 2; ++ni)
          acc[mi][ni] = __builtin_amdgcn_mfma_f32_16x16x32_bf16(af[mi], bf[ni],
                                                                acc[mi][ni], 0, 0, 0);
    }
  }

#pragma unroll
  for (int mi = 0; mi < 4; ++mi) {
#pragma unroll
    for (int ni = 0; ni < 2; ++ni) {
      int row0 = bm + mi * 16 + ((l >> 4) << 2);
      int col = bn + w * 32 + ni * 16 + (l & 15);
      float bv = BIAS_RELU ? bias[col] : 0.f;
      f32x4 v = acc[mi][ni];
#pragma unroll
      for (int r = 0; r < 4; ++r) {
        float val = v[r];
        if (BIAS_RELU) val = fmaxf(val + bv, 0.f);
        if (OUT_BF16)
          ((unsigned short*)C)[(size_t)(row0 + r) * N + col] = f2bf(val);
        else
          ((float*)C)[(size_t)(row0 + r) * N + col] = val;
      }
    }
  }
}

// ---- launch ----
extern "C" void kernel_launch(void* const* d_in, const int* in_sizes, int n_in,
                              void* d_out, int out_size, void* d_ws, size_t ws_size,
                              hipStream_t stream) {
  const float* dm = (const float*)d_in[0];
  const float* fm = (const float*)d_in[1];
  const float* W1 = (const float*)d_in[2];
  const float* b1 = (const float*)d_in[3];
  const float* W2 = (const float*)d_in[4];
  const float* b2 = (const float*)d_in[5];
  float* out = (float*)d_out;

  char* ws = (char*)d_ws;
  int*                tgt   = (int*)(ws + 0x000000);               // 256KB
  int*                deg   = (int*)(ws + 0x040000);               // 64KB
  float*              dinv  = (float*)(ws + 0x050000);             // 64KB
  int*                off   = (int*)(ws + 0x060000);               // 64KB+4
  int*                cur   = (int*)(ws + 0x080000);               // 64KB+4
  int*                srcs  = (int*)(ws + 0x0A0000);               // 320KB
  unsigned long long* skeys = (unsigned long long*)(ws + 0x100000);// 128KB
  int*                bstart= (int*)(ws + 0x140000);               // 64KB+4
  unsigned long long* tmpkeys = (unsigned long long*)(ws + 0x170000); // 128KB
  unsigned short*     W1t   = (unsigned short*)(ws + 0x190000);    // 256KB
  unsigned short*     W2t   = (unsigned short*)(ws + 0x1D0000);    // 256KB
  unsigned short*     px0   = (unsigned short*)(ws + 0x0400000);   // 8MB
  unsigned short*     px    = (unsigned short*)(ws + 0x0C00000);   // 8MB
  unsigned short*     h1    = (unsigned short*)(ws + 0x1400000);   // 16MB
  unsigned short*     t2    = (unsigned short*)(ws + 0x2400000);   // 8MB
  float*              xout  = (float*)(ws + 0x2C00000);            // 16MB
  (void)ws_size; (void)in_sizes; (void)n_in; (void)out_size;

  // ---- graph build: 5 kernels (wide fused bucket stage, rank-free select) ----
  bucket_kernel<<<NB, 1024, 0, stream>>>(dm, tmpkeys, bstart, deg);
  bfinal_kernel<<<64, 256, 0, stream>>>(tmpkeys, bstart, skeys);
  knn_select_kernel<<<64, 256, 0, stream>>>(skeys, tgt, deg);
  scan_kernel<<<1, 256, 0, stream>>>(deg, dinv, off, cur);
  fill_csr_kernel<<<NEDGE / 256, 256, 0, stream>>>(tgt, cur, srcs);

  // ---- all input conversions in one launch (fm batches + both weights) ----
  cvt_all_kernel<<<dim3(128, 8, NB + 1), 256, 0, stream>>>(fm, px0, W1, W1t, W2, W2t);

  // layer 1: propagate then GEMM relu(.@W1+b1) -> bf16
  prop_kernel<<<N_NODES / 8, 256, 0, stream>>>(px0, px, off, srcs, dinv);
  gemm_bf16_kernel<true, true><<<dim3(256, 4), 256, 0, stream>>>(
      px, W1t, h1, b1, 16384, 512, 256);

  // layer 2: GEMM h1@W2 -> bf16, then propagate+bias+relu (f32 node-major)
  gemm_bf16_kernel<false, true><<<dim3(256, 2), 256, 0, stream>>>(
      h1, W2t, t2, nullptr, 16384, 256, 512);
  prop2_kernel<<<N_NODES / 8, 256, 0, stream>>>(t2, xout, off, srcs, dinv, b2);

  // node-major -> [B][256][4096]
  transpose_kernel<<<dim3(8, 128, NB), 256, 0, stream>>>(xout, out, 4096, 256);
}